// Round 13
// baseline (205.778 us; speedup 1.0000x reference)
//
#include <hip/hip_runtime.h>
#include <stdint.h>

#define ALPHA_C 1000.0f
#define EPS_C 1e-6f
#define NPTS 8192
#define TOTQ 65536
#define G 16
#define TPB 1024
#define HCAP 640   // halo: 144 cells, Poisson(288); P(>640) ~ 0 (fallback backs it)
#define QCAP 256   // core: 32 cells, Poisson(64); P(>256) ~ 0
#define FBCAP 512
// grid: 4 pairs x 128 macros (4x4x2 cells); halo box 6x6x4 cells.
// occupancy: 2 blocks/CU x 16 waves = 32 waves/CU (LDS ~63 KB, VGPR <= 64)

// ws layout: bests u64[8][NPTS] = bytes [0, 524288)
//   word 131072: probe (never written -> uniform 0xAA poison baseline B)
//   words 131073..131076: done[4] (per-pair arrival counters, baseline B)
//   word 131077: done2 (pair-finalizer counter, baseline B)
//   words 131080..131083: pair_sum f32[4]
#define W_PROBE 131072
#define W_DONE 131073
#define W_DONE2 131077
#define W_PSUM 131080

__device__ __forceinline__ unsigned enc_d(float d) {  // order-preserving bits
  unsigned sb = __float_as_uint(d);
  return sb ^ (((unsigned)((int)sb >> 31)) | 0x80000000u);
}
__device__ __forceinline__ float dec_d(unsigned sb) {
  return __uint_as_float((sb & 0x80000000u) ? (sb ^ 0x80000000u) : ~sb);
}

// exact d in the reference's fp ordering ((xx - 2xy) + yy, left-to-right dot
// chains); min key => argmin with ties -> smaller idx (matches jnp.argmin)
#define EVAL(PX, PY, PZ, IDX)                                                  \
  {                                                                            \
    float yy = __fadd_rn(__fadd_rn(__fmul_rn(PX, PX), __fmul_rn(PY, PY)),      \
                         __fmul_rn(PZ, PZ));                                   \
    float xy = __fadd_rn(__fadd_rn(__fmul_rn(qx, PX), __fmul_rn(qy, PY)),      \
                         __fmul_rn(qz, PZ));                                   \
    float d = __fadd_rn(__fsub_rn(xx, __fmul_rn(2.0f, xy)), yy);               \
    unsigned long long k = ((unsigned long long)enc_d(d) << 32) |              \
                           (unsigned long long)(IDX);                          \
    if (k < bkey) bkey = k;                                                    \
  }

// ---------------------------------------------------------------------------
// Single dispatch. Each of 512 blocks: dual-direction macro query (R12,
// unchanged). Then a NON-BLOCKING tail: per-pair done counter (poison-
// baseline); the 128th block of pair b computes both directions' density-
// aware loss (LDS histogram) from the completed bests, stores pair_sum[b];
// the 4th pair-finalizer writes out[0] = 1 - total/TOTQ (single plain store).
// ---------------------------------------------------------------------------
__global__ __launch_bounds__(TPB, 8) void dacd_kernel(
    const float* __restrict__ x, const float* __restrict__ y,
    unsigned* __restrict__ w, float* __restrict__ out) {
  __shared__ float4 halo_x[HCAP + 8], halo_y[HCAP + 8];
  __shared__ float4 qlist_x[QCAP], qlist_y[QCAP];
  __shared__ unsigned short fb[FBCAP];
  __shared__ unsigned nhx_s, nhy_s, nqx_s, nqy_s, nfb_s;
  __shared__ unsigned long long red[TPB / 64];
  __shared__ unsigned hist[NPTS];  // 32 KB (loss tail only)
  __shared__ float wred[TPB / 64];
  __shared__ bool isLast_s;

  unsigned long long* bests_g = (unsigned long long*)w;
  unsigned B = w[W_PROBE];

  int tid = threadIdx.x, bid = blockIdx.x;
  int b = bid >> 7, m = bid & 127;
  int mx = m & 3, my = (m >> 2) & 3, mz = m >> 4;  // macro = 4x4x2 cells
  const float* xb = x + b * NPTS * 3;
  const float* yb = y + b * NPTS * 3;
  unsigned long long* bests0 = bests_g + (size_t)b * NPTS;        // dir0: x->y
  unsigned long long* bests1 = bests_g + (size_t)(4 + b) * NPTS;  // dir1: y->x

  int hx0 = mx * 4 - 1, hx1 = mx * 4 + 5;
  int hy0 = my * 4 - 1, hy1 = my * 4 + 5;
  int hz0 = mz * 2 - 1, hz1 = mz * 2 + 3;
  // h = 2^-4: p*16 float compares == integer cell tests, exactly
  float hlx = (float)hx0, hhx = (float)hx1, hly = (float)hy0, hhy = (float)hy1,
        hlz = (float)hz0, hhz = (float)hz1;
  float qlx = (float)(mx * 4), qhx = (float)(mx * 4 + 4);
  float qly = (float)(my * 4), qhy = (float)(my * 4 + 4);
  float qlz = (float)(mz * 2), qhz = (float)(mz * 2 + 2);

  if (tid == 0) { nhx_s = 0u; nhy_s = 0u; nqx_s = 0u; nqy_s = 0u; nfb_s = 0u; }
  __syncthreads();

  // Phase A: one float4-chunked stream per cloud; halo + core compaction.
  const float4* xp4 = (const float4*)xb;
  const float4* yp4 = (const float4*)yb;
#pragma unroll
  for (int c = tid; c < NPTS / 4; c += TPB) {
    float4 f0 = xp4[c * 3], f1 = xp4[c * 3 + 1], f2 = xp4[c * 3 + 2];
    float px[4] = {f0.x, f0.w, f1.z, f2.y};
    float py[4] = {f0.y, f1.x, f1.w, f2.z};
    float pz[4] = {f0.z, f1.y, f2.x, f2.w};
#pragma unroll
    for (int u = 0; u < 4; u++) {
      float tx = px[u] * 16.0f, ty = py[u] * 16.0f, tz = pz[u] * 16.0f;
      if (tx >= hlx && tx < hhx && ty >= hly && ty < hhy && tz >= hlz &&
          tz < hhz) {
        float4 v = (float4){px[u], py[u], pz[u],
                            __uint_as_float((unsigned)(c * 4 + u))};
        unsigned pos = atomicAdd(&nhx_s, 1u);
        if (pos < HCAP) halo_x[pos] = v;
        if (tx >= qlx && tx < qhx && ty >= qly && ty < qhy && tz >= qlz &&
            tz < qhz) {
          unsigned qpos = atomicAdd(&nqx_s, 1u);
          if (qpos < QCAP) qlist_x[qpos] = v;
        }
      }
    }
  }
#pragma unroll
  for (int c = tid; c < NPTS / 4; c += TPB) {
    float4 f0 = yp4[c * 3], f1 = yp4[c * 3 + 1], f2 = yp4[c * 3 + 2];
    float px[4] = {f0.x, f0.w, f1.z, f2.y};
    float py[4] = {f0.y, f1.x, f1.w, f2.z};
    float pz[4] = {f0.z, f1.y, f2.x, f2.w};
#pragma unroll
    for (int u = 0; u < 4; u++) {
      float tx = px[u] * 16.0f, ty = py[u] * 16.0f, tz = pz[u] * 16.0f;
      if (tx >= hlx && tx < hhx && ty >= hly && ty < hhy && tz >= hlz &&
          tz < hhz) {
        float4 v = (float4){px[u], py[u], pz[u],
                            __uint_as_float((unsigned)(c * 4 + u))};
        unsigned pos = atomicAdd(&nhy_s, 1u);
        if (pos < HCAP) halo_y[pos] = v;
        if (tx >= qlx && tx < qhx && ty >= qly && ty < qhy && tz >= qlz &&
            tz < qhz) {
          unsigned qpos = atomicAdd(&nqy_s, 1u);
          if (qpos < QCAP) qlist_y[qpos] = v;
        }
      }
    }
  }
  __syncthreads();
  unsigned nhx = nhx_s, nhy = nhy_s, nqx = nqx_s, nqy = nqy_s;
  bool okx = (nhx <= HCAP), oky = (nhy <= HCAP);
  unsigned nh8x = (nhx + 7) & ~7u, nh8y = (nhy + 7) & ~7u;
  const float4 sent = {100.0f, 100.0f, 100.0f, __uint_as_float(0xFFFFu)};
  if (okx && tid < (int)(nh8x - nhx)) halo_x[nhx + tid] = sent;
  if (oky && tid < (int)(nh8y - nhy)) halo_y[nhy + tid] = sent;
  if (nqx > QCAP) nqx = QCAP;
  if (nqy > QCAP) nqy = QCAP;
  __syncthreads();

  // Phase B: fused both-direction queries, 8 lanes per query.
  const float h = 1.0f / (float)G;
  int j = tid & 7, g = tid >> 3;  // 128 groups
  unsigned ntot = nqx + nqy;
  for (unsigned qi = g; qi < ntot; qi += TPB / 8) {
    bool isx = (qi < nqx);  // x query -> scan halo_y (dir0)
    float4 qf = isx ? qlist_x[qi] : qlist_y[qi - nqx];
    const float4* cand = isx ? halo_y : halo_x;
    unsigned nh8 = isx ? nh8y : nh8x;
    bool cok = isx ? oky : okx;
    float qx = qf.x, qy = qf.y, qz = qf.z;
    float xx = __fadd_rn(__fadd_rn(__fmul_rn(qx, qx), __fmul_rn(qy, qy)),
                         __fmul_rn(qz, qz));
    unsigned long long bkey = ~0ull;
    if (cok) {
#pragma unroll 4
      for (unsigned it = j; it < nh8; it += 8) {
        float4 pt = cand[it];
        EVAL(pt.x, pt.y, pt.z, __float_as_uint(pt.w));
      }
    }
    unsigned long long o = __shfl_xor(bkey, 1, 64);
    if (o < bkey) bkey = o;
    o = __shfl_xor(bkey, 2, 64);
    if (o < bkey) bkey = o;
    o = __shfl_xor(bkey, 4, 64);
    if (o < bkey) bkey = o;
    bool ok = false;
    if (cok && bkey != ~0ull &&
        (unsigned)(bkey & 0xFFFFFFFFull) != 0xFFFFu) {
      float mm = 1e30f;  // margin to nearest interior halo face
      if (hx0 > 0) mm = fminf(mm, qx - hlx * h);
      if (hx1 < G) mm = fminf(mm, hhx * h - qx);
      if (hy0 > 0) mm = fminf(mm, qy - hly * h);
      if (hy1 < G) mm = fminf(mm, hhy * h - qy);
      if (hz0 > 0) mm = fminf(mm, qz - hlz * h);
      if (hz1 < G) mm = fminf(mm, hhz * h - qz);
      float bd = dec_d((unsigned)(bkey >> 32));
      ok = (mm >= 1e29f) || (bd <= mm * mm);
    }
    if (j == 0) {
      if (ok) {
        (isx ? bests0 : bests1)[__float_as_uint(qf.w)] = bkey;
      } else {
        unsigned fpos = atomicAdd(&nfb_s, 1u);
        if (fpos < FBCAP) fb[fpos] = (unsigned short)qi;
      }
    }
  }
  __syncthreads();

  // Rare fallback: block-cooperative exact full scan from global.
  unsigned nfb = nfb_s;
  if (nfb > FBCAP) nfb = FBCAP;
  for (unsigned f = 0; f < nfb; f++) {
    unsigned qi = fb[f];
    bool isx = (qi < nqx);
    float4 qf = isx ? qlist_x[qi] : qlist_y[qi - nqx];
    const float* cp = isx ? yb : xb;
    float qx = qf.x, qy = qf.y, qz = qf.z;
    float xx = __fadd_rn(__fadd_rn(__fmul_rn(qx, qx), __fmul_rn(qy, qy)),
                         __fmul_rn(qz, qz));
    unsigned long long bkey = ~0ull;
    for (int p0 = tid; p0 < NPTS; p0 += TPB) {
      float px = cp[p0 * 3], py = cp[p0 * 3 + 1], pz = cp[p0 * 3 + 2];
      EVAL(px, py, pz, (unsigned)p0);
    }
#pragma unroll
    for (int o2 = 1; o2 < 64; o2 <<= 1) {
      unsigned long long o = __shfl_xor(bkey, o2, 64);
      if (o < bkey) bkey = o;
    }
    if ((tid & 63) == 0) red[tid >> 6] = bkey;
    __syncthreads();
    if (tid == 0) {
      unsigned long long k = red[0];
#pragma unroll
      for (int r2 = 1; r2 < TPB / 64; r2++)
        if (red[r2] < k) k = red[r2];
      (isx ? bests0 : bests1)[__float_as_uint(qf.w)] = k;
    }
    __syncthreads();
  }

  // ---- Non-blocking tail: last block of each pair computes the pair loss ---
  __threadfence();  // release this block's bests stores (device scope)
  __syncthreads();
  if (tid == 0)
    isLast_s = ((atomicAdd(w + W_DONE + b, 1u) - B) == 127u);
  __syncthreads();
  if (!isLast_s) return;
  __threadfence();  // acquire: invalidate caches before reading others' bests

  float v = 0.0f;
  for (int dir = 0; dir < 2; dir++) {
    const unsigned long long* bd = bests_g + (size_t)(dir * 4 + b) * NPTS;
    for (int k = tid; k < NPTS; k += TPB) hist[k] = 0u;
    __syncthreads();
    unsigned long long kk[NPTS / TPB];
#pragma unroll
    for (int k = 0; k < NPTS / TPB; k++) {
      kk[k] = bd[tid + k * TPB];
      atomicAdd(&hist[(unsigned)kk[k] & (NPTS - 1)], 1u);
    }
    __syncthreads();
#pragma unroll
    for (int k = 0; k < NPTS / TPB; k++) {
      unsigned idx = (unsigned)kk[k] & (NPTS - 1);
      float d = dec_d((unsigned)(kk[k] >> 32));
      v += expf(-d * ALPHA_C) / ((float)hist[idx] + EPS_C);
    }
    __syncthreads();  // before re-zeroing hist for dir 1
  }
#pragma unroll
  for (int o = 32; o > 0; o >>= 1) v += __shfl_down(v, o, 64);
  if ((tid & 63) == 0) wred[tid >> 6] = v;
  __syncthreads();
  if (tid == 0) {
    float t = 0.0f;
#pragma unroll
    for (int k = 0; k < TPB / 64; k++) t += wred[k];
    ((float*)w)[W_PSUM + b] = t;
    __threadfence();  // release pair_sum
    if ((atomicAdd(w + W_DONE2, 1u) - B) == 3u) {
      __threadfence();  // acquire pair_sums
      const float* ps = (const float*)w + W_PSUM;
      out[0] = 1.0f - (ps[0] + ps[1] + ps[2] + ps[3]) * (1.0f / (float)TOTQ);
    }
  }
}

extern "C" void kernel_launch(void* const* d_in, const int* in_sizes, int n_in,
                              void* d_out, int out_size, void* d_ws,
                              size_t ws_size, hipStream_t stream) {
  const float* x = (const float*)d_in[0];
  const float* y = (const float*)d_in[1];
  dacd_kernel<<<512, TPB, 0, stream>>>(x, y, (unsigned*)d_ws, (float*)d_out);
}

// Round 14
// 82.074 us; speedup vs baseline: 2.5072x; 2.5072x over previous
//
#include <hip/hip_runtime.h>
#include <stdint.h>

#define ALPHA_C 1000.0f
#define EPS_C 1e-6f
#define NPTS 8192
#define TOTQ 65536
#define G 16
#define TPB 1024
#define HCAP 640   // halo: 144 cells, Poisson(288); P(>640) ~ 0 (fallback backs it)
#define QCAP 256   // core: 32 cells, Poisson(64); P(>256) ~ 0
#define FBCAP 512
// grid: 4 pairs x 128 macros (4x4x2 cells); halo box 6x6x4 cells.
// occupancy: 2 blocks/CU (LDS ~62 KB), 32 waves/CU.

// ws layout: bests u64[8][NPTS] = bytes [0, 524288)
//   word 131072: probe (never written -> uniform 0xAA poison baseline B)
//   words 131073..131076: done[4] (per-pair arrival counters, baseline B)
//   word 131077: done2 (pair-finalizer counter, baseline B)
//   words 131080..131083: pair_sum f32[4] (atomicExch-published)
#define W_PROBE 131072
#define W_DONE 131073
#define W_DONE2 131077
#define W_PSUM 131080

__device__ __forceinline__ unsigned enc_d(float d) {  // order-preserving bits
  unsigned sb = __float_as_uint(d);
  return sb ^ (((unsigned)((int)sb >> 31)) | 0x80000000u);
}
__device__ __forceinline__ float dec_d(unsigned sb) {
  return __uint_as_float((sb & 0x80000000u) ? (sb ^ 0x80000000u) : ~sb);
}

// exact d in the reference's fp ordering ((xx - 2xy) + yy, left-to-right dot
// chains); min key => argmin with ties -> smaller idx (matches jnp.argmin)
#define EVAL(PX, PY, PZ, IDX)                                                  \
  {                                                                            \
    float yy = __fadd_rn(__fadd_rn(__fmul_rn(PX, PX), __fmul_rn(PY, PY)),      \
                         __fmul_rn(PZ, PZ));                                   \
    float xy = __fadd_rn(__fadd_rn(__fmul_rn(qx, PX), __fmul_rn(qy, PY)),      \
                         __fmul_rn(qz, PZ));                                   \
    float d = __fadd_rn(__fsub_rn(xx, __fmul_rn(2.0f, xy)), yy);               \
    unsigned long long k = ((unsigned long long)enc_d(d) << 32) |              \
                           (unsigned long long)(IDX);                          \
    if (k < bkey) bkey = k;                                                    \
  }

#define BEST_STORE(PTR, VAL)                                                   \
  __hip_atomic_store((PTR), (VAL), __ATOMIC_RELAXED, __HIP_MEMORY_SCOPE_AGENT)
#define BEST_LOAD(PTR)                                                         \
  __hip_atomic_load((PTR), __ATOMIC_RELAXED, __HIP_MEMORY_SCOPE_AGENT)

// ---------------------------------------------------------------------------
// Single dispatch, FENCE-FREE. R12's dual-direction macro query; all cross-
// block data (bests, pair_sum) moves through device-scope atomics only (no
// plain stores -> no dirty L2 -> no buffer_wbl2). __syncthreads drains each
// wave's vmcnt before the done-counter increments (compiler-guaranteed
// s_waitcnt vmcnt(0) before s_barrier).
// ---------------------------------------------------------------------------
__global__ __launch_bounds__(TPB, 8) void dacd_kernel(
    const float* __restrict__ x, const float* __restrict__ y,
    unsigned* __restrict__ w, float* __restrict__ out) {
  __shared__ float4 halo_x[HCAP + 8], halo_y[HCAP + 8];
  __shared__ float4 qlist_x[QCAP], qlist_y[QCAP];
  __shared__ unsigned short fb[FBCAP];
  __shared__ unsigned nhx_s, nhy_s, nqx_s, nqy_s, nfb_s;
  __shared__ unsigned long long red[TPB / 64];
  __shared__ unsigned hist[NPTS];  // 32 KB (loss tail only)
  __shared__ float wred[TPB / 64];
  __shared__ bool isLast_s;

  unsigned long long* bests_g = (unsigned long long*)w;
  unsigned B = w[W_PROBE];

  int tid = threadIdx.x, bid = blockIdx.x;
  int b = bid >> 7, m = bid & 127;
  int mx = m & 3, my = (m >> 2) & 3, mz = m >> 4;  // macro = 4x4x2 cells
  const float* xb = x + b * NPTS * 3;
  const float* yb = y + b * NPTS * 3;
  unsigned long long* bests0 = bests_g + (size_t)b * NPTS;        // dir0: x->y
  unsigned long long* bests1 = bests_g + (size_t)(4 + b) * NPTS;  // dir1: y->x

  int hx0 = mx * 4 - 1, hx1 = mx * 4 + 5;
  int hy0 = my * 4 - 1, hy1 = my * 4 + 5;
  int hz0 = mz * 2 - 1, hz1 = mz * 2 + 3;
  // h = 2^-4: p*16 float compares == integer cell tests, exactly
  float hlx = (float)hx0, hhx = (float)hx1, hly = (float)hy0, hhy = (float)hy1,
        hlz = (float)hz0, hhz = (float)hz1;
  float qlx = (float)(mx * 4), qhx = (float)(mx * 4 + 4);
  float qly = (float)(my * 4), qhy = (float)(my * 4 + 4);
  float qlz = (float)(mz * 2), qhz = (float)(mz * 2 + 2);

  if (tid == 0) { nhx_s = 0u; nhy_s = 0u; nqx_s = 0u; nqy_s = 0u; nfb_s = 0u; }
  __syncthreads();

  // Phase A: one float4-chunked stream per cloud; halo + core compaction.
  const float4* xp4 = (const float4*)xb;
  const float4* yp4 = (const float4*)yb;
#pragma unroll
  for (int c = tid; c < NPTS / 4; c += TPB) {
    float4 f0 = xp4[c * 3], f1 = xp4[c * 3 + 1], f2 = xp4[c * 3 + 2];
    float px[4] = {f0.x, f0.w, f1.z, f2.y};
    float py[4] = {f0.y, f1.x, f1.w, f2.z};
    float pz[4] = {f0.z, f1.y, f2.x, f2.w};
#pragma unroll
    for (int u = 0; u < 4; u++) {
      float tx = px[u] * 16.0f, ty = py[u] * 16.0f, tz = pz[u] * 16.0f;
      if (tx >= hlx && tx < hhx && ty >= hly && ty < hhy && tz >= hlz &&
          tz < hhz) {
        float4 v = (float4){px[u], py[u], pz[u],
                            __uint_as_float((unsigned)(c * 4 + u))};
        unsigned pos = atomicAdd(&nhx_s, 1u);
        if (pos < HCAP) halo_x[pos] = v;
        if (tx >= qlx && tx < qhx && ty >= qly && ty < qhy && tz >= qlz &&
            tz < qhz) {
          unsigned qpos = atomicAdd(&nqx_s, 1u);
          if (qpos < QCAP) qlist_x[qpos] = v;
        }
      }
    }
  }
#pragma unroll
  for (int c = tid; c < NPTS / 4; c += TPB) {
    float4 f0 = yp4[c * 3], f1 = yp4[c * 3 + 1], f2 = yp4[c * 3 + 2];
    float px[4] = {f0.x, f0.w, f1.z, f2.y};
    float py[4] = {f0.y, f1.x, f1.w, f2.z};
    float pz[4] = {f0.z, f1.y, f2.x, f2.w};
#pragma unroll
    for (int u = 0; u < 4; u++) {
      float tx = px[u] * 16.0f, ty = py[u] * 16.0f, tz = pz[u] * 16.0f;
      if (tx >= hlx && tx < hhx && ty >= hly && ty < hhy && tz >= hlz &&
          tz < hhz) {
        float4 v = (float4){px[u], py[u], pz[u],
                            __uint_as_float((unsigned)(c * 4 + u))};
        unsigned pos = atomicAdd(&nhy_s, 1u);
        if (pos < HCAP) halo_y[pos] = v;
        if (tx >= qlx && tx < qhx && ty >= qly && ty < qhy && tz >= qlz &&
            tz < qhz) {
          unsigned qpos = atomicAdd(&nqy_s, 1u);
          if (qpos < QCAP) qlist_y[qpos] = v;
        }
      }
    }
  }
  __syncthreads();
  unsigned nhx = nhx_s, nhy = nhy_s, nqx = nqx_s, nqy = nqy_s;
  bool okx = (nhx <= HCAP), oky = (nhy <= HCAP);
  unsigned nh8x = (nhx + 7) & ~7u, nh8y = (nhy + 7) & ~7u;
  const float4 sent = {100.0f, 100.0f, 100.0f, __uint_as_float(0xFFFFu)};
  if (okx && tid < (int)(nh8x - nhx)) halo_x[nhx + tid] = sent;
  if (oky && tid < (int)(nh8y - nhy)) halo_y[nhy + tid] = sent;
  if (nqx > QCAP) nqx = QCAP;
  if (nqy > QCAP) nqy = QCAP;
  __syncthreads();

  // Phase B: fused both-direction queries, 8 lanes per query.
  const float h = 1.0f / (float)G;
  int j = tid & 7, g = tid >> 3;  // 128 groups
  unsigned ntot = nqx + nqy;
  for (unsigned qi = g; qi < ntot; qi += TPB / 8) {
    bool isx = (qi < nqx);  // x query -> scan halo_y (dir0)
    float4 qf = isx ? qlist_x[qi] : qlist_y[qi - nqx];
    const float4* cand = isx ? halo_y : halo_x;
    unsigned nh8 = isx ? nh8y : nh8x;
    bool cok = isx ? oky : okx;
    float qx = qf.x, qy = qf.y, qz = qf.z;
    float xx = __fadd_rn(__fadd_rn(__fmul_rn(qx, qx), __fmul_rn(qy, qy)),
                         __fmul_rn(qz, qz));
    unsigned long long bkey = ~0ull;
    if (cok) {
#pragma unroll 4
      for (unsigned it = j; it < nh8; it += 8) {
        float4 pt = cand[it];
        EVAL(pt.x, pt.y, pt.z, __float_as_uint(pt.w));
      }
    }
    unsigned long long o = __shfl_xor(bkey, 1, 64);
    if (o < bkey) bkey = o;
    o = __shfl_xor(bkey, 2, 64);
    if (o < bkey) bkey = o;
    o = __shfl_xor(bkey, 4, 64);
    if (o < bkey) bkey = o;
    bool ok = false;
    if (cok && bkey != ~0ull &&
        (unsigned)(bkey & 0xFFFFFFFFull) != 0xFFFFu) {
      float mm = 1e30f;  // margin to nearest interior halo face
      if (hx0 > 0) mm = fminf(mm, qx - hlx * h);
      if (hx1 < G) mm = fminf(mm, hhx * h - qx);
      if (hy0 > 0) mm = fminf(mm, qy - hly * h);
      if (hy1 < G) mm = fminf(mm, hhy * h - qy);
      if (hz0 > 0) mm = fminf(mm, qz - hlz * h);
      if (hz1 < G) mm = fminf(mm, hhz * h - qz);
      float bd = dec_d((unsigned)(bkey >> 32));
      ok = (mm >= 1e29f) || (bd <= mm * mm);
    }
    if (j == 0) {
      if (ok) {
        BEST_STORE((isx ? bests0 : bests1) + __float_as_uint(qf.w), bkey);
      } else {
        unsigned fpos = atomicAdd(&nfb_s, 1u);
        if (fpos < FBCAP) fb[fpos] = (unsigned short)qi;
      }
    }
  }
  __syncthreads();

  // Rare fallback: block-cooperative exact full scan from global.
  unsigned nfb = nfb_s;
  if (nfb > FBCAP) nfb = FBCAP;
  for (unsigned f = 0; f < nfb; f++) {
    unsigned qi = fb[f];
    bool isx = (qi < nqx);
    float4 qf = isx ? qlist_x[qi] : qlist_y[qi - nqx];
    const float* cp = isx ? yb : xb;
    float qx = qf.x, qy = qf.y, qz = qf.z;
    float xx = __fadd_rn(__fadd_rn(__fmul_rn(qx, qx), __fmul_rn(qy, qy)),
                         __fmul_rn(qz, qz));
    unsigned long long bkey = ~0ull;
    for (int p0 = tid; p0 < NPTS; p0 += TPB) {
      float px = cp[p0 * 3], py = cp[p0 * 3 + 1], pz = cp[p0 * 3 + 2];
      EVAL(px, py, pz, (unsigned)p0);
    }
#pragma unroll
    for (int o2 = 1; o2 < 64; o2 <<= 1) {
      unsigned long long o = __shfl_xor(bkey, o2, 64);
      if (o < bkey) bkey = o;
    }
    if ((tid & 63) == 0) red[tid >> 6] = bkey;
    __syncthreads();
    if (tid == 0) {
      unsigned long long k = red[0];
#pragma unroll
      for (int r2 = 1; r2 < TPB / 64; r2++)
        if (red[r2] < k) k = red[r2];
      BEST_STORE((isx ? bests0 : bests1) + __float_as_uint(qf.w), k);
    }
    __syncthreads();
  }

  // ---- Fence-free tail: __syncthreads drained all waves' atomic stores to
  // the coherent point; relaxed done-counter; 128th block of the pair runs
  // the loss from atomic loads. NO __threadfence anywhere.
  __syncthreads();
  if (tid == 0)
    isLast_s = ((atomicAdd(w + W_DONE + b, 1u) - B) == 127u);
  __syncthreads();
  if (!isLast_s) return;

  float v = 0.0f;
  for (int dir = 0; dir < 2; dir++) {
    const unsigned long long* bd = bests_g + (size_t)(dir * 4 + b) * NPTS;
    for (int k = tid; k < NPTS; k += TPB) hist[k] = 0u;
    __syncthreads();
    unsigned long long kk[NPTS / TPB];
#pragma unroll
    for (int k = 0; k < NPTS / TPB; k++) {
      kk[k] = BEST_LOAD(bd + tid + k * TPB);
      atomicAdd(&hist[(unsigned)kk[k] & (NPTS - 1)], 1u);
    }
    __syncthreads();
#pragma unroll
    for (int k = 0; k < NPTS / TPB; k++) {
      unsigned idx = (unsigned)kk[k] & (NPTS - 1);
      float d = dec_d((unsigned)(kk[k] >> 32));
      v += expf(-d * ALPHA_C) / ((float)hist[idx] + EPS_C);
    }
    __syncthreads();  // before re-zeroing hist for dir 1
  }
#pragma unroll
  for (int o = 32; o > 0; o >>= 1) v += __shfl_down(v, o, 64);
  if ((tid & 63) == 0) wred[tid >> 6] = v;
  __syncthreads();
  if (tid == 0) {
    float t = 0.0f;
#pragma unroll
    for (int k = 0; k < TPB / 64; k++) t += wred[k];
    // publish pair sum via atomic exchange (coherent point, no fence)
    (void)atomicExch(w + W_PSUM + b, __float_as_uint(t));
    __builtin_amdgcn_s_waitcnt(0);  // exch complete before done2 increment
    if ((atomicAdd(w + W_DONE2, 1u) - B) == 3u) {
      float s0 = __uint_as_float(__hip_atomic_load(
          w + W_PSUM + 0, __ATOMIC_RELAXED, __HIP_MEMORY_SCOPE_AGENT));
      float s1 = __uint_as_float(__hip_atomic_load(
          w + W_PSUM + 1, __ATOMIC_RELAXED, __HIP_MEMORY_SCOPE_AGENT));
      float s2 = __uint_as_float(__hip_atomic_load(
          w + W_PSUM + 2, __ATOMIC_RELAXED, __HIP_MEMORY_SCOPE_AGENT));
      float s3 = __uint_as_float(__hip_atomic_load(
          w + W_PSUM + 3, __ATOMIC_RELAXED, __HIP_MEMORY_SCOPE_AGENT));
      out[0] = 1.0f - (s0 + s1 + s2 + s3) * (1.0f / (float)TOTQ);
    }
  }
}

extern "C" void kernel_launch(void* const* d_in, const int* in_sizes, int n_in,
                              void* d_out, int out_size, void* d_ws,
                              size_t ws_size, hipStream_t stream) {
  const float* x = (const float*)d_in[0];
  const float* y = (const float*)d_in[1];
  dacd_kernel<<<512, TPB, 0, stream>>>(x, y, (unsigned*)d_ws, (float*)d_out);
}

// Round 15
// 77.441 us; speedup vs baseline: 2.6572x; 1.0598x over previous
//
#include <hip/hip_runtime.h>
#include <stdint.h>

#define ALPHA_C 1000.0f
#define EPS_C 1e-6f
#define NPTS 8192
#define TOTQ 65536
#define G 16
#define TPB 1024
#define HCAP 640   // halo: 144 cells, Poisson(288); P(>640) ~ 0 (fallback backs it)
#define QCAP 256   // core: 32 cells, Poisson(64); P(>256) ~ 0
#define FBCAP 512
// grid: 4 pairs x 128 macros (4x4x2 cells); halo box 6x6x4 cells.
// occupancy: 2 blocks/CU x 16 waves = 32 waves/CU (VGPR <= 64, LDS ~30 KB)

__device__ __forceinline__ unsigned enc_d(float d) {  // order-preserving bits
  unsigned sb = __float_as_uint(d);
  return sb ^ (((unsigned)((int)sb >> 31)) | 0x80000000u);
}
__device__ __forceinline__ float dec_d(unsigned sb) {
  return __uint_as_float((sb & 0x80000000u) ? (sb ^ 0x80000000u) : ~sb);
}

// exact d in the reference's fp ordering ((xx - 2xy) + yy, left-to-right dot
// chains); min key => argmin with ties -> smaller idx (matches jnp.argmin)
#define EVAL(PX, PY, PZ, IDX)                                                  \
  {                                                                            \
    float yy = __fadd_rn(__fadd_rn(__fmul_rn(PX, PX), __fmul_rn(PY, PY)),      \
                         __fmul_rn(PZ, PZ));                                   \
    float xy = __fadd_rn(__fadd_rn(__fmul_rn(qx, PX), __fmul_rn(qy, PY)),      \
                         __fmul_rn(qz, PZ));                                   \
    float d = __fadd_rn(__fsub_rn(xx, __fmul_rn(2.0f, xy)), yy);               \
    unsigned long long k = ((unsigned long long)enc_d(d) << 32) |              \
                           (unsigned long long)(IDX);                          \
    if (k < bkey) bkey = k;                                                    \
  }

// ---------------------------------------------------------------------------
// K1: dual-direction macro query. Each of 512 blocks streams BOTH clouds of
// its pair once, building halo_x/halo_y (+ core qlist_x/qlist_y) in LDS, then
// 128 8-lane groups answer both directions' queries with broadcast flat
// scans. Exact margin vs halo-box faces; rare misses -> cooperative full scan.
// ---------------------------------------------------------------------------
__global__ __launch_bounds__(TPB, 8) void query_kernel(
    const float* __restrict__ x, const float* __restrict__ y,
    unsigned long long* __restrict__ bests_g, float* __restrict__ out) {
  __shared__ float4 halo_x[HCAP + 8], halo_y[HCAP + 8];
  __shared__ float4 qlist_x[QCAP], qlist_y[QCAP];
  __shared__ unsigned short fb[FBCAP];
  __shared__ unsigned nhx_s, nhy_s, nqx_s, nqy_s, nfb_s;
  __shared__ unsigned long long red[TPB / 64];

  int tid = threadIdx.x, bid = blockIdx.x;
  if (bid == 0 && tid == 0) out[0] = 1.0f;  // loss kernel subtracts
  int b = bid >> 7, m = bid & 127;
  int mx = m & 3, my = (m >> 2) & 3, mz = m >> 4;  // macro = 4x4x2 cells
  const float* xb = x + b * NPTS * 3;
  const float* yb = y + b * NPTS * 3;
  unsigned long long* bests0 = bests_g + (size_t)b * NPTS;        // dir0: x->y
  unsigned long long* bests1 = bests_g + (size_t)(4 + b) * NPTS;  // dir1: y->x

  int hx0 = mx * 4 - 1, hx1 = mx * 4 + 5;
  int hy0 = my * 4 - 1, hy1 = my * 4 + 5;
  int hz0 = mz * 2 - 1, hz1 = mz * 2 + 3;
  // h = 2^-4: p*16 float compares == integer cell tests, exactly
  float hlx = (float)hx0, hhx = (float)hx1, hly = (float)hy0, hhy = (float)hy1,
        hlz = (float)hz0, hhz = (float)hz1;
  float qlx = (float)(mx * 4), qhx = (float)(mx * 4 + 4);
  float qly = (float)(my * 4), qhy = (float)(my * 4 + 4);
  float qlz = (float)(mz * 2), qhz = (float)(mz * 2 + 2);

  if (tid == 0) { nhx_s = 0u; nhy_s = 0u; nqx_s = 0u; nqy_s = 0u; nfb_s = 0u; }
  __syncthreads();

  // Phase A: one float4-chunked stream per cloud; halo + core compaction.
  const float4* xp4 = (const float4*)xb;
  const float4* yp4 = (const float4*)yb;
#pragma unroll
  for (int c = tid; c < NPTS / 4; c += TPB) {
    float4 f0 = xp4[c * 3], f1 = xp4[c * 3 + 1], f2 = xp4[c * 3 + 2];
    float px[4] = {f0.x, f0.w, f1.z, f2.y};
    float py[4] = {f0.y, f1.x, f1.w, f2.z};
    float pz[4] = {f0.z, f1.y, f2.x, f2.w};
#pragma unroll
    for (int u = 0; u < 4; u++) {
      float tx = px[u] * 16.0f, ty = py[u] * 16.0f, tz = pz[u] * 16.0f;
      if (tx >= hlx && tx < hhx && ty >= hly && ty < hhy && tz >= hlz &&
          tz < hhz) {
        float4 v = (float4){px[u], py[u], pz[u],
                            __uint_as_float((unsigned)(c * 4 + u))};
        unsigned pos = atomicAdd(&nhx_s, 1u);
        if (pos < HCAP) halo_x[pos] = v;
        if (tx >= qlx && tx < qhx && ty >= qly && ty < qhy && tz >= qlz &&
            tz < qhz) {
          unsigned qpos = atomicAdd(&nqx_s, 1u);
          if (qpos < QCAP) qlist_x[qpos] = v;
        }
      }
    }
  }
#pragma unroll
  for (int c = tid; c < NPTS / 4; c += TPB) {
    float4 f0 = yp4[c * 3], f1 = yp4[c * 3 + 1], f2 = yp4[c * 3 + 2];
    float px[4] = {f0.x, f0.w, f1.z, f2.y};
    float py[4] = {f0.y, f1.x, f1.w, f2.z};
    float pz[4] = {f0.z, f1.y, f2.x, f2.w};
#pragma unroll
    for (int u = 0; u < 4; u++) {
      float tx = px[u] * 16.0f, ty = py[u] * 16.0f, tz = pz[u] * 16.0f;
      if (tx >= hlx && tx < hhx && ty >= hly && ty < hhy && tz >= hlz &&
          tz < hhz) {
        float4 v = (float4){px[u], py[u], pz[u],
                            __uint_as_float((unsigned)(c * 4 + u))};
        unsigned pos = atomicAdd(&nhy_s, 1u);
        if (pos < HCAP) halo_y[pos] = v;
        if (tx >= qlx && tx < qhx && ty >= qly && ty < qhy && tz >= qlz &&
            tz < qhz) {
          unsigned qpos = atomicAdd(&nqy_s, 1u);
          if (qpos < QCAP) qlist_y[qpos] = v;
        }
      }
    }
  }
  __syncthreads();
  unsigned nhx = nhx_s, nhy = nhy_s, nqx = nqx_s, nqy = nqy_s;
  bool okx = (nhx <= HCAP), oky = (nhy <= HCAP);
  unsigned nh8x = (nhx + 7) & ~7u, nh8y = (nhy + 7) & ~7u;
  const float4 sent = {100.0f, 100.0f, 100.0f, __uint_as_float(0xFFFFu)};
  if (okx && tid < (int)(nh8x - nhx)) halo_x[nhx + tid] = sent;
  if (oky && tid < (int)(nh8y - nhy)) halo_y[nhy + tid] = sent;
  if (nqx > QCAP) nqx = QCAP;
  if (nqy > QCAP) nqy = QCAP;
  __syncthreads();

  // Phase B: fused both-direction queries, 8 lanes per query.
  const float h = 1.0f / (float)G;
  int j = tid & 7, g = tid >> 3;  // 128 groups
  unsigned ntot = nqx + nqy;
  for (unsigned qi = g; qi < ntot; qi += TPB / 8) {
    bool isx = (qi < nqx);  // x query -> scan halo_y (dir0)
    float4 qf = isx ? qlist_x[qi] : qlist_y[qi - nqx];
    const float4* cand = isx ? halo_y : halo_x;
    unsigned nh8 = isx ? nh8y : nh8x;
    bool cok = isx ? oky : okx;
    float qx = qf.x, qy = qf.y, qz = qf.z;
    float xx = __fadd_rn(__fadd_rn(__fmul_rn(qx, qx), __fmul_rn(qy, qy)),
                         __fmul_rn(qz, qz));
    unsigned long long bkey = ~0ull;
    if (cok) {
#pragma unroll 4
      for (unsigned it = j; it < nh8; it += 8) {
        float4 pt = cand[it];
        EVAL(pt.x, pt.y, pt.z, __float_as_uint(pt.w));
      }
    }
    unsigned long long o = __shfl_xor(bkey, 1, 64);
    if (o < bkey) bkey = o;
    o = __shfl_xor(bkey, 2, 64);
    if (o < bkey) bkey = o;
    o = __shfl_xor(bkey, 4, 64);
    if (o < bkey) bkey = o;
    bool ok = false;
    if (cok && bkey != ~0ull &&
        (unsigned)(bkey & 0xFFFFFFFFull) != 0xFFFFu) {
      float mm = 1e30f;  // margin to nearest interior halo face
      if (hx0 > 0) mm = fminf(mm, qx - hlx * h);
      if (hx1 < G) mm = fminf(mm, hhx * h - qx);
      if (hy0 > 0) mm = fminf(mm, qy - hly * h);
      if (hy1 < G) mm = fminf(mm, hhy * h - qy);
      if (hz0 > 0) mm = fminf(mm, qz - hlz * h);
      if (hz1 < G) mm = fminf(mm, hhz * h - qz);
      float bd = dec_d((unsigned)(bkey >> 32));
      ok = (mm >= 1e29f) || (bd <= mm * mm);
    }
    if (j == 0) {
      if (ok) {
        (isx ? bests0 : bests1)[__float_as_uint(qf.w)] = bkey;
      } else {
        unsigned fpos = atomicAdd(&nfb_s, 1u);
        if (fpos < FBCAP) fb[fpos] = (unsigned short)qi;
      }
    }
  }
  __syncthreads();

  // Rare fallback: block-cooperative exact full scan from global.
  unsigned nfb = nfb_s;
  if (nfb > FBCAP) nfb = FBCAP;
  for (unsigned f = 0; f < nfb; f++) {
    unsigned qi = fb[f];
    bool isx = (qi < nqx);
    float4 qf = isx ? qlist_x[qi] : qlist_y[qi - nqx];
    const float* cp = isx ? yb : xb;
    float qx = qf.x, qy = qf.y, qz = qf.z;
    float xx = __fadd_rn(__fadd_rn(__fmul_rn(qx, qx), __fmul_rn(qy, qy)),
                         __fmul_rn(qz, qz));
    unsigned long long bkey = ~0ull;
    for (int p0 = tid; p0 < NPTS; p0 += TPB) {
      float px = cp[p0 * 3], py = cp[p0 * 3 + 1], pz = cp[p0 * 3 + 2];
      EVAL(px, py, pz, (unsigned)p0);
    }
#pragma unroll
    for (int o2 = 1; o2 < 64; o2 <<= 1) {
      unsigned long long o = __shfl_xor(bkey, o2, 64);
      if (o < bkey) bkey = o;
    }
    if ((tid & 63) == 0) red[tid >> 6] = bkey;
    __syncthreads();
    if (tid == 0) {
      unsigned long long k = red[0];
#pragma unroll
      for (int r2 = 1; r2 < TPB / 64; r2++)
        if (red[r2] < k) k = red[r2];
      (isx ? bests0 : bests1)[__float_as_uint(qf.w)] = k;
    }
    __syncthreads();
  }
}

// ---------------------------------------------------------------------------
// K2: per (dir,b) block: LDS histogram of NN indices over 8192 bests, then
// sum exp(-alpha*d)/(cnt+eps); atomicAdd(-sum/TOTQ) into out (seeded 1.0).
// ---------------------------------------------------------------------------
#define LTPB 1024
__global__ __launch_bounds__(LTPB) void loss_kernel(
    const unsigned long long* __restrict__ bests_g, float* __restrict__ out) {
  __shared__ unsigned hist[NPTS];  // 32 KB
  __shared__ float wred[LTPB / 64];
  const unsigned long long* bests = bests_g + (size_t)blockIdx.x * NPTS;
  int tid = threadIdx.x;
  for (int k = tid; k < NPTS; k += LTPB) hist[k] = 0u;
  __syncthreads();
  unsigned long long kk[NPTS / LTPB];
#pragma unroll
  for (int k = 0; k < NPTS / LTPB; k++) {
    kk[k] = bests[tid + k * LTPB];
    atomicAdd(&hist[(unsigned)kk[k] & (NPTS - 1)], 1u);
  }
  __syncthreads();
  float v = 0.0f;
#pragma unroll
  for (int k = 0; k < NPTS / LTPB; k++) {
    unsigned idx = (unsigned)kk[k] & (NPTS - 1);
    float d = dec_d((unsigned)(kk[k] >> 32));
    v += expf(-d * ALPHA_C) / ((float)hist[idx] + EPS_C);
  }
#pragma unroll
  for (int o = 32; o > 0; o >>= 1) v += __shfl_down(v, o, 64);
  if ((tid & 63) == 0) wred[tid >> 6] = v;
  __syncthreads();
  if (tid == 0) {
    float t = 0.0f;
#pragma unroll
    for (int k = 0; k < LTPB / 64; k++) t += wred[k];
    atomicAdd(out, -t * (1.0f / (float)TOTQ));
  }
}

extern "C" void kernel_launch(void* const* d_in, const int* in_sizes, int n_in,
                              void* d_out, int out_size, void* d_ws,
                              size_t ws_size, hipStream_t stream) {
  const float* x = (const float*)d_in[0];
  const float* y = (const float*)d_in[1];
  float* out = (float*)d_out;
  unsigned long long* bests = (unsigned long long*)d_ws;  // u64[8][NPTS]

  query_kernel<<<512, TPB, 0, stream>>>(x, y, bests, out);
  loss_kernel<<<8, LTPB, 0, stream>>>(bests, out);
}